// Round 5
// baseline (265.496 us; speedup 1.0000x reference)
//
#include <hip/hip_runtime.h>
#include <math.h>

// ws layout (uint32 words):
//   [0     .. 16384)  histC  (exact low-bits hist over selected 2^14 window)
//   [16384 .. 20480)  hist12 (top-12-bit histogram)
//   [20480 .. 20544)  hist64 (64 sub-bins of width 2^14 within selected b12)
//   [20544 .. 20560)  ctrl: [0]=b12 (0xFFFFFFFF=none) [1]=kprime [2]=thr_bits
//                           [3]=cand_count [4]=win_lo_bits (0xFFFFFFFF=none)
//                           [5]=kpp [6]=m_bin
//   [20560 .. +CAP)   candidate x values (float) of selected b12
#define HC_OFF     0u
#define H12_OFF    16384u
#define H64_OFF    20480u
#define CTRL_OFF   20544u
#define ZERO_WORDS 20560u
#define CAND_OFF   20560u
#define CAND_CAP   900000u     // 3.6 MB total ws use (proven available in r3)
#define LBUF       2048u       // per-block LDS candidate buffer

#define FLOOR_BITS 0x36000000u // bits(2^-19): below this, cheap is unreliable

// --- exact softplus (UNCHANGED from passing rounds 1-4) ------------------
__device__ __forceinline__ float softplus_exact(float x) {
    float ax = fabsf(x);
    float e = (float)exp(-(double)ax);
    float l = (float)log1p((double)e);
    return fmaxf(x, 0.0f) + l;
}
__device__ __forceinline__ unsigned exact_bits(float x) {
    return __float_as_uint(softplus_exact(x));
}

// --- refinement: hand-rolled cheap softplus + margin-gated exact ----------
// DETERMINISTIC function of x: recomputing it reproduces stored bits exactly.
__device__ __forceinline__ unsigned refine_A(float x, float* spo) {
    float ax = fabsf(x);
    float e = __expf(-ax);
    float sp = fmaxf(x, 0.0f) + __logf(1.0f + e);
    unsigned cb = __float_as_uint(sp);
    float mf = 64.0f + 8.0f * ax;
    if (x < 0.0f) mf += __builtin_amdgcn_rcpf(e);   // e^{ax} term
    bool need = (cb < FLOOR_BITS) || (mf >= 524288.0f);
    if (!need) {
        unsigned m = (unsigned)mf;
        unsigned low = cb & 0xFFFFFu;
        need = (low < m) || (low >= 0x100000u - m);
    }
    if (need) {
        sp = softplus_exact(x);
        cb = __float_as_uint(sp);
    }
    *spo = sp;
    return cb;
}

// --- kA: stream logits+targets; store refined bits to out; hist12 --------
// unknown: out = +loss (refined bits). known: out = -(loss) (sign tag).
__global__ __launch_bounds__(256) void kA_store_hist(
    const float* __restrict__ lg, const float* __restrict__ tg,
    float* __restrict__ out, unsigned* __restrict__ ws, long long n) {
    __shared__ unsigned sh[4096];
    for (int i = threadIdx.x; i < 4096; i += 256) sh[i] = 0;
    __syncthreads();

    long long n4 = n >> 2;
    long long tid = (long long)blockIdx.x * 256 + threadIdx.x;
    long long stride = (long long)gridDim.x * 256;
    const float4* lg4 = (const float4*)lg;
    const float4* tg4 = (const float4*)tg;
    float4* out4 = (float4*)out;

    for (long long i = tid; i < n4; i += stride) {
        float4 x4 = lg4[i];
        float4 t4 = tg4[i];
        float xs[4] = {x4.x, x4.y, x4.z, x4.w};
        float ts[4] = {t4.x, t4.y, t4.z, t4.w};
        float os[4];
#pragma unroll
        for (int c = 0; c < 4; ++c) {
            float x = xs[c], t = ts[c];
            if (isnan(t)) {
                float sp;
                unsigned cb = refine_A(x, &sp);
                if (cb != 0u) atomicAdd(&sh[cb >> 20], 1u);
                os[c] = __uint_as_float(cb);
            } else {
                float ax = fabsf(x);
                float sp = fmaxf(x, 0.0f) + __logf(1.0f + __expf(-ax));
                float loss = sp - x * t;            // >= 0 always
                os[c] = __uint_as_float(__float_as_uint(loss) ^ 0x80000000u);
            }
        }
        float4 o = {os[0], os[1], os[2], os[3]};
        out4[i] = o;
    }
    if (tid == 0) {   // scalar tail (n % 4 == 0 here; kept for generality)
        for (long long i = (n4 << 2); i < n; ++i) {
            float x = lg[i], t = tg[i];
            if (isnan(t)) {
                float sp;
                unsigned cb = refine_A(x, &sp);
                if (cb != 0u) atomicAdd(&sh[0], 0u), atomicAdd(&sh[cb >> 20], 1u);
                out[i] = __uint_as_float(cb);
            } else {
                float sp = fmaxf(x, 0.0f) + __logf(1.0f + __expf(-fabsf(x)));
                float loss = sp - x * t;
                out[i] = __uint_as_float(__float_as_uint(loss) ^ 0x80000000u);
            }
        }
    }
    __syncthreads();
    unsigned* hist12 = ws + H12_OFF;
    for (int i = threadIdx.x; i < 4096; i += 256)
        if (sh[i]) atomicAdd(&hist12[i], sh[i]);
}

// --- k2: select 12-bit bin; compute k, kprime, and bin-wide margin -------
__global__ __launch_bounds__(256) void k2_sel12(
    unsigned* __restrict__ ws, const int* __restrict__ epoch_ptr) {
    const unsigned* hist12 = ws + H12_OFF;
    unsigned* ctrl = ws + CTRL_OFF;
    __shared__ unsigned long long chunk[256];
    int t = threadIdx.x;
    unsigned long long s = 0;
    for (int j = 0; j < 16; ++j) s += hist12[t * 16 + j];
    chunk[t] = s;
    __syncthreads();
    if (t == 0) {
        unsigned long long tot = 0;
        for (int c = 0; c < 256; ++c) tot += chunk[c];
        int epoch = epoch_ptr[0];
        float percent = fminf((float)epoch * 0.1f, 1.0f);
        float nf = (float)tot;              // astype(float32)
        float kr = rintf(nf * percent);     // jnp.round half-to-even
        long long k = (long long)kr;        // astype(int32)
        if (k < 1) k = 1;

        long long cum = 0;
        int b = -1;
        long long kprime = 0;
        for (int c = 255; c >= 0; --c) {
            if (cum + (long long)chunk[c] >= k) {
                long long cc = cum;
                for (int j = 15; j >= 0; --j) {
                    unsigned v = hist12[c * 16 + j];
                    if (cc + (long long)v >= k) {
                        b = c * 16 + j;
                        kprime = k - cc;
                        break;
                    }
                    cc += v;
                }
                break;
            }
            cum += chunk[c];
        }
        ctrl[0] = (unsigned)b;
        ctrl[1] = (unsigned)kprime;
        if (b < 0) {
            ctrl[2] = 0u;                   // threshold = 0.0f
            ctrl[4] = 0xFFFFFFFFu;          // no window
            ctrl[6] = 0u;
        } else {
            // bin-wide margin: worst per-element cheap-error over the bin's
            // x-range (unknown loss = softplus(x) is monotone in x).
            unsigned lo12 = (unsigned)b << 20;
            double vlo = (double)__uint_as_float(lo12);
            double vhi = (double)__uint_as_float(lo12 + 0xFFFFFu);
            double mb = 1e9;
            if (vlo > 1e-30) {
                double xlo = vlo + log1p(-exp(-vlo)) - 0.001;  // inv_softplus
                double xhi = vhi + log1p(-exp(-vhi)) + 0.001;
                double axmax = fmax(fabs(xlo), fabs(xhi));
                mb = 64.0 + 8.0 * ceil(axmax);
                if (xlo < 0.0) mb += exp(fmin(-xlo, 30.0));
                mb *= 2.0;                  // safety factor
            }
            ctrl[6] = (mb >= 8192.0) ? 8192u : (unsigned)mb;
        }
    }
}

// --- kB: 64-sub-bin histogram within selected bin + candidate compaction --
// Compaction is per-block LDS-buffered: one global atomicAdd per block.
__global__ __launch_bounds__(256) void kB_hist64(
    const float* __restrict__ lg, const unsigned* __restrict__ ob,
    unsigned* __restrict__ ws, long long n) {
    unsigned b12 = ws[CTRL_OFF + 0];
    if (b12 == 0xFFFFFFFFu) return;
    unsigned lo12 = b12 << 20;
    unsigned hi12 = lo12 + (1u << 20);
    unsigned m = ws[CTRL_OFF + 6];

    __shared__ unsigned sh[64];
    __shared__ float buf[LBUF];
    __shared__ unsigned lcnt, gbase;
    if (threadIdx.x < 64) sh[threadIdx.x] = 0;
    if (threadIdx.x == 0) lcnt = 0;
    __syncthreads();

    float* cand = (float*)(ws + CAND_OFF);
    unsigned* cnt = ws + CTRL_OFF + 3;

    long long n4 = n >> 2;
    long long tid = (long long)blockIdx.x * 256 + threadIdx.x;
    long long stride = (long long)gridDim.x * 256;
    const uint4* o4 = (const uint4*)ob;

    for (long long i = tid; i < n4; i += stride) {
        uint4 u4 = o4[i];
        unsigned us[4] = {u4.x, u4.y, u4.z, u4.w};
#pragma unroll
        for (int c = 0; c < 4; ++c) {
            unsigned u = us[c];
            // knowns have sign bit set -> u >= 2^31 > hi12 -> excluded
            if (u != 0u && u >= lo12 && u < hi12) {
                float x = lg[i * 4 + c];
                unsigned rB = u;
                unsigned d = u & 16383u;
                if (d < m || d >= 16384u - m)
                    rB = exact_bits(x);           // edge: resolve exactly
                atomicAdd(&sh[(rB >> 14) & 63u], 1u);
                unsigned li = atomicAdd(&lcnt, 1u);   // LDS atomic
                if (li < LBUF) buf[li] = x;
            }
        }
    }
    if (tid == 0) {  // scalar tail (empty for n % 4 == 0): direct append
        for (long long i = (n4 << 2); i < n; ++i) {
            unsigned u = ob[i];
            if (u != 0u && u >= lo12 && u < hi12) {
                float x = lg[i];
                unsigned rB = u;
                unsigned d = u & 16383u;
                if (d < m || d >= 16384u - m) rB = exact_bits(x);
                atomicAdd(&sh[(rB >> 14) & 63u], 1u);
                unsigned idx = atomicAdd(cnt, 1u);
                if (idx < CAND_CAP) cand[idx] = x;
            }
        }
    }
    __syncthreads();
    if (threadIdx.x < 64 && sh[threadIdx.x])
        atomicAdd(&ws[H64_OFF + threadIdx.x], sh[threadIdx.x]);
    // flush candidate buffer: one reservation per block
    if (threadIdx.x == 0) {
        // on LDS overflow, poison the count so kC takes the rescan fallback
        unsigned add = (lcnt > LBUF) ? (CAND_CAP + 1u) : lcnt;
        gbase = atomicAdd(cnt, add);
    }
    __syncthreads();
    unsigned c2 = lcnt < LBUF ? lcnt : LBUF;
    for (unsigned j = threadIdx.x; j < c2; j += 256) {
        unsigned gi = gbase + j;
        if (gi < CAND_CAP) cand[gi] = buf[j];
    }
}

// --- k4: select 2^14-wide window ------------------------------------------
__global__ void k4_sel64(unsigned* __restrict__ ws) {
    unsigned* ctrl = ws + CTRL_OFF;
    if (ctrl[0] == 0xFFFFFFFFu) return;
    if (threadIdx.x == 0) {
        long long kprime = (long long)ctrl[1];
        long long cum = 0;
        int s = 0;
        long long kpp = 1;
        for (int j = 63; j >= 0; --j) {
            unsigned v = ws[H64_OFF + j];
            if (cum + (long long)v >= kprime) {
                s = j;
                kpp = kprime - cum;
                break;
            }
            cum += v;
        }
        ctrl[4] = (ctrl[0] << 20) + ((unsigned)s << 14);
        ctrl[5] = (unsigned)kpp;
    }
}

// --- kC: exact histogram over the selected window (candidate-list scan) ---
__global__ __launch_bounds__(256) void kC_histwin(
    const float* __restrict__ lg, const unsigned* __restrict__ ob,
    unsigned* __restrict__ ws, long long n) {
    unsigned wlo = ws[CTRL_OFF + 4];
    if (wlo == 0xFFFFFFFFu) return;
    unsigned whi = wlo + 16384u;
    unsigned m = ws[CTRL_OFF + 6];
    unsigned b12 = ws[CTRL_OFF + 0];
    unsigned lo12 = b12 << 20;
    unsigned hi12 = lo12 + (1u << 20);
    unsigned glo = (wlo - lo12 > m) ? wlo - m : lo12;
    unsigned ghi = (hi12 - whi > m) ? whi + m : hi12;
    unsigned count = ws[CTRL_OFF + 3];

    long long tid = (long long)blockIdx.x * 256 + threadIdx.x;
    long long stride = (long long)gridDim.x * 256;

    if (count <= CAND_CAP) {
        const float* cand = (const float*)(ws + CAND_OFF);
        for (long long i = tid; i < (long long)count; i += stride) {
            float x = cand[i];
            float spd;
            unsigned u = refine_A(x, &spd);   // bit-identical to stored bits
            if (u >= glo && u < ghi) {
                unsigned eb = exact_bits(x);
                unsigned rB = u;
                unsigned d = u & 16383u;
                if (d < m || d >= 16384u - m) rB = eb;
                if (rB >= wlo && rB < whi) {
                    unsigned off = eb - wlo;
                    if (off < 16384u) atomicAdd(&ws[HC_OFF + off], 1u);
                }
            }
        }
    } else {
        // overflow fallback: rescan full out array (never expected)
        long long n4 = n >> 2;
        const uint4* o4 = (const uint4*)ob;
        for (long long i = tid; i < n4; i += stride) {
            uint4 u4 = o4[i];
            unsigned us[4] = {u4.x, u4.y, u4.z, u4.w};
#pragma unroll
            for (int c = 0; c < 4; ++c) {
                unsigned u = us[c];
                if (u != 0u && u >= glo && u < ghi) {
                    float x = lg[i * 4 + c];
                    unsigned eb = exact_bits(x);
                    unsigned rB = u;
                    unsigned d = u & 16383u;
                    if (d < m || d >= 16384u - m) rB = eb;
                    if (rB >= wlo && rB < whi) {
                        unsigned off = eb - wlo;
                        if (off < 16384u) atomicAdd(&ws[HC_OFF + off], 1u);
                    }
                }
            }
        }
        if (tid == 0) {
            for (long long i = (n4 << 2); i < n; ++i) {
                unsigned u = ob[i];
                if (u != 0u && u >= glo && u < ghi) {
                    unsigned eb = exact_bits(lg[i]);
                    unsigned rB = u;
                    unsigned d = u & 16383u;
                    if (d < m || d >= 16384u - m) rB = eb;
                    if (rB >= wlo && rB < whi) {
                        unsigned off = eb - wlo;
                        if (off < 16384u) atomicAdd(&ws[HC_OFF + off], 1u);
                    }
                }
            }
        }
    }
}

// --- k6: exact threshold bits from histC ----------------------------------
__global__ __launch_bounds__(1024) void k6_selwin(unsigned* __restrict__ ws) {
    unsigned* ctrl = ws + CTRL_OFF;
    if (ctrl[4] == 0xFFFFFFFFu) return;
    __shared__ unsigned long long csum[1024];
    int t = threadIdx.x;
    unsigned long long s = 0;
    for (int j = 0; j < 16; ++j) s += ws[HC_OFF + t * 16 + j];
    csum[t] = s;
    __syncthreads();
    if (t == 0) {
        long long kpp = (long long)ctrl[5];
        long long cum = 0;
        int sel = 0;
        long long rem = kpp;
        for (int c = 1023; c >= 0; --c) {
            if (cum + (long long)csum[c] >= kpp) {
                sel = c;
                rem = kpp - cum;
                break;
            }
            cum += csum[c];
        }
        long long cc = 0;
        int bsel = 0;
        for (int j = 15; j >= 0; --j) {
            unsigned v = ws[HC_OFF + sel * 16 + j];
            if (cc + (long long)v >= rem) {
                bsel = j;
                break;
            }
            cc += v;
        }
        ctrl[2] = ctrl[4] + (unsigned)(sel * 16 + bsel);
    }
}

// --- kD: final in-place rewrite of out -------------------------------------
__global__ __launch_bounds__(256) void kD_final(
    const float* __restrict__ lg, unsigned* __restrict__ ob,
    const unsigned* __restrict__ ws, long long n) {
    unsigned thr = ws[CTRL_OFF + 2];
    unsigned m = ws[CTRL_OFF + 6];

    long long n4 = n >> 2;
    long long tid = (long long)blockIdx.x * 256 + threadIdx.x;
    long long stride = (long long)gridDim.x * 256;
    uint4* o4 = (uint4*)ob;

    for (long long i = tid; i < n4; i += stride) {
        uint4 u4 = o4[i];
        unsigned us[4] = {u4.x, u4.y, u4.z, u4.w};
        unsigned vs[4];
#pragma unroll
        for (int c = 0; c < 4; ++c) {
            unsigned u = us[c];
            if (u & 0x80000000u) {
                vs[c] = u ^ 0x80000000u;            // known: restore loss
            } else {
                unsigned udiff = (u > thr) ? u - thr : thr - u;
                if (udiff <= m) {                   // banded: exact decision
                    unsigned eb = exact_bits(lg[i * 4 + c]);
                    vs[c] = (eb > thr) ? 0u : eb;
                } else {
                    vs[c] = (u > thr) ? 0u : u;
                }
            }
        }
        uint4 v4 = {vs[0], vs[1], vs[2], vs[3]};
        o4[i] = v4;
    }
    if (tid == 0) {
        for (long long i = (n4 << 2); i < n; ++i) {
            unsigned u = ob[i];
            if (u & 0x80000000u) {
                ob[i] = u ^ 0x80000000u;
            } else {
                unsigned udiff = (u > thr) ? u - thr : thr - u;
                if (udiff <= m) {
                    unsigned eb = exact_bits(lg[i]);
                    ob[i] = (eb > thr) ? 0u : eb;
                } else {
                    ob[i] = (u > thr) ? 0u : u;
                }
            }
        }
    }
}

extern "C" void kernel_launch(void* const* d_in, const int* in_sizes, int n_in,
                              void* d_out, int out_size, void* d_ws, size_t ws_size,
                              hipStream_t stream) {
    const float* lg = (const float*)d_in[0];
    const float* tg = (const float*)d_in[1];
    const int* epoch = (const int*)d_in[2];
    float* out = (float*)d_out;
    unsigned* ob = (unsigned*)d_out;
    unsigned* ws = (unsigned*)d_ws;
    long long n = (long long)in_sizes[0];

    hipMemsetAsync(d_ws, 0, (size_t)ZERO_WORDS * 4, stream);

    const int blocks = 2048, threads = 256;
    kA_store_hist<<<blocks, threads, 0, stream>>>(lg, tg, out, ws, n);
    k2_sel12<<<1, 256, 0, stream>>>(ws, epoch);
    kB_hist64<<<blocks, threads, 0, stream>>>(lg, ob, ws, n);
    k4_sel64<<<1, 64, 0, stream>>>(ws);
    kC_histwin<<<1024, threads, 0, stream>>>(lg, ob, ws, n);
    k6_selwin<<<1, 1024, 0, stream>>>(ws);
    kD_final<<<blocks, threads, 0, stream>>>(lg, ob, ws, n);
}

// Round 6
// 257.462 us; speedup vs baseline: 1.0312x; 1.0312x over previous
//
#include <hip/hip_runtime.h>
#include <math.h>

// ws layout (uint32 words):
//   [0     .. 16384)  histC  (exact low-bits hist over selected 2^14 window)
//   [16384 .. 20480)  hist12 (top-12-bit histogram)
//   [20480 .. 20544)  hist64 (64 sub-bins of width 2^14 within selected b12)
//   [20544 .. 20560)  ctrl: [0]=b12 (0xFFFFFFFF=none) [1]=kprime [2]=thr_bits
//                           [3]=cand_count [4]=win_lo_bits (0xFFFFFFFF=none)
//                           [5]=kpp [6]=m_bin
//   [20560 .. +CAP)   candidate x values (float) of selected b12
#define HC_OFF     0u
#define H12_OFF    16384u
#define H64_OFF    20480u
#define CTRL_OFF   20544u
#define ZERO_WORDS 20560u
#define CAND_OFF   20560u
#define CAND_CAP   900000u     // 3.6 MB total ws use (proven available in r3)
#define LBUF       2048u       // per-block LDS candidate buffer

#define FLOOR_BITS 0x36000000u // bits(2^-19): below this, cheap is unreliable

// --- exact softplus (UNCHANGED from passing rounds 1-5) ------------------
__device__ __forceinline__ float softplus_exact(float x) {
    float ax = fabsf(x);
    float e = (float)exp(-(double)ax);
    float l = (float)log1p((double)e);
    return fmaxf(x, 0.0f) + l;
}
__device__ __forceinline__ unsigned exact_bits(float x) {
    return __float_as_uint(softplus_exact(x));
}

// --- refinement core: margin-gated exact, given precomputed ax/e/sp ------
// DETERMINISTIC function of x: recomputing reproduces stored bits exactly.
__device__ __forceinline__ unsigned refine_core(float x, float ax, float e,
                                                float sp) {
    unsigned cb = __float_as_uint(sp);
    float mf = 64.0f + 8.0f * ax;
    if (x < 0.0f) mf += __builtin_amdgcn_rcpf(e);   // e^{ax} term
    bool need = (cb < FLOOR_BITS) || (mf >= 524288.0f);
    if (!need) {
        unsigned m = (unsigned)mf;
        unsigned low = cb & 0xFFFFFu;
        need = (low < m) || (low >= 0x100000u - m);
    }
    if (need) cb = exact_bits(x);
    return cb;
}
__device__ __forceinline__ unsigned refine_A(float x, float* spo) {
    float ax = fabsf(x);
    float e = __expf(-ax);
    float sp = fmaxf(x, 0.0f) + __logf(1.0f + e);
    *spo = sp;
    return refine_core(x, ax, e, sp);
}

// --- kA per-element: branchless shared exp/log core ----------------------
__device__ __forceinline__ unsigned kA_elem(float x, float t,
                                            unsigned* __restrict__ sh) {
    float ax = fabsf(x);
    float e = __expf(-ax);
    float sp = fmaxf(x, 0.0f) + __logf(1.0f + e);   // shared by both paths
    unsigned outb;
    if (isnan(t)) {
        unsigned cb = refine_core(x, ax, e, sp);    // bit == refine_A(x)
        if (cb != 0u) atomicAdd(&sh[cb >> 20], 1u);
        outb = cb;
    } else {
        float loss = sp - x * t;                    // >= 0 always
        outb = __float_as_uint(loss) ^ 0x80000000u; // sign tag: known
    }
    return outb;
}

// --- kA: stream logits+targets; store refined bits to out; hist12 --------
// unknown: out = +loss (refined bits). known: out = -(loss) (sign tag).
// 2x-unrolled: 32 B/lane/iter, 4 loads in flight before compute.
__global__ __launch_bounds__(256) void kA_store_hist(
    const float* __restrict__ lg, const float* __restrict__ tg,
    float* __restrict__ out, unsigned* __restrict__ ws, long long n) {
    __shared__ unsigned sh[4096];
    for (int i = threadIdx.x; i < 4096; i += 256) sh[i] = 0;
    __syncthreads();

    long long n8 = n >> 3;
    long long tid = (long long)blockIdx.x * 256 + threadIdx.x;
    long long stride = (long long)gridDim.x * 256;
    const float4* lg4 = (const float4*)lg;
    const float4* tg4 = (const float4*)tg;
    float4* out4 = (float4*)out;

    for (long long i = tid; i < n8; i += stride) {
        float4 xa = lg4[2 * i];
        float4 xb = lg4[2 * i + 1];
        float4 ta = tg4[2 * i];
        float4 tb = tg4[2 * i + 1];
        float4 oa, ob_;
        oa.x = __uint_as_float(kA_elem(xa.x, ta.x, sh));
        oa.y = __uint_as_float(kA_elem(xa.y, ta.y, sh));
        oa.z = __uint_as_float(kA_elem(xa.z, ta.z, sh));
        oa.w = __uint_as_float(kA_elem(xa.w, ta.w, sh));
        ob_.x = __uint_as_float(kA_elem(xb.x, tb.x, sh));
        ob_.y = __uint_as_float(kA_elem(xb.y, tb.y, sh));
        ob_.z = __uint_as_float(kA_elem(xb.z, tb.z, sh));
        ob_.w = __uint_as_float(kA_elem(xb.w, tb.w, sh));
        out4[2 * i] = oa;
        out4[2 * i + 1] = ob_;
    }
    if (tid == 0) {   // scalar tail (n % 8 == 0 here; kept for generality)
        for (long long i = (n8 << 3); i < n; ++i)
            out[i] = __uint_as_float(kA_elem(lg[i], tg[i], sh));
    }
    __syncthreads();
    unsigned* hist12 = ws + H12_OFF;
    for (int i = threadIdx.x; i < 4096; i += 256)
        if (sh[i]) atomicAdd(&hist12[i], sh[i]);
}

// --- k2: select 12-bit bin; compute k, kprime, and bin-wide margin -------
__global__ __launch_bounds__(256) void k2_sel12(
    unsigned* __restrict__ ws, const int* __restrict__ epoch_ptr) {
    const unsigned* hist12 = ws + H12_OFF;
    unsigned* ctrl = ws + CTRL_OFF;
    __shared__ unsigned long long chunk[256];
    int t = threadIdx.x;
    unsigned long long s = 0;
    for (int j = 0; j < 16; ++j) s += hist12[t * 16 + j];
    chunk[t] = s;
    __syncthreads();
    if (t == 0) {
        unsigned long long tot = 0;
        for (int c = 0; c < 256; ++c) tot += chunk[c];
        int epoch = epoch_ptr[0];
        float percent = fminf((float)epoch * 0.1f, 1.0f);
        float nf = (float)tot;              // astype(float32)
        float kr = rintf(nf * percent);     // jnp.round half-to-even
        long long k = (long long)kr;        // astype(int32)
        if (k < 1) k = 1;

        long long cum = 0;
        int b = -1;
        long long kprime = 0;
        for (int c = 255; c >= 0; --c) {
            if (cum + (long long)chunk[c] >= k) {
                long long cc = cum;
                for (int j = 15; j >= 0; --j) {
                    unsigned v = hist12[c * 16 + j];
                    if (cc + (long long)v >= k) {
                        b = c * 16 + j;
                        kprime = k - cc;
                        break;
                    }
                    cc += v;
                }
                break;
            }
            cum += chunk[c];
        }
        ctrl[0] = (unsigned)b;
        ctrl[1] = (unsigned)kprime;
        if (b < 0) {
            ctrl[2] = 0u;                   // threshold = 0.0f
            ctrl[4] = 0xFFFFFFFFu;          // no window
            ctrl[6] = 0u;
        } else {
            // bin-wide margin: worst per-element cheap-error over the bin's
            // x-range (unknown loss = softplus(x) is monotone in x).
            unsigned lo12 = (unsigned)b << 20;
            double vlo = (double)__uint_as_float(lo12);
            double vhi = (double)__uint_as_float(lo12 + 0xFFFFFu);
            double mb = 1e9;
            if (vlo > 1e-30) {
                double xlo = vlo + log1p(-exp(-vlo)) - 0.001;  // inv_softplus
                double xhi = vhi + log1p(-exp(-vhi)) + 0.001;
                double axmax = fmax(fabs(xlo), fabs(xhi));
                mb = 64.0 + 8.0 * ceil(axmax);
                if (xlo < 0.0) mb += exp(fmin(-xlo, 30.0));
                mb *= 2.0;                  // safety factor
            }
            ctrl[6] = (mb >= 8192.0) ? 8192u : (unsigned)mb;
        }
    }
}

// --- kB: 64-sub-bin histogram within selected bin + candidate compaction --
// Compaction is per-block LDS-buffered: one global atomicAdd per block.
__global__ __launch_bounds__(256) void kB_hist64(
    const float* __restrict__ lg, const unsigned* __restrict__ ob,
    unsigned* __restrict__ ws, long long n) {
    unsigned b12 = ws[CTRL_OFF + 0];
    if (b12 == 0xFFFFFFFFu) return;
    unsigned lo12 = b12 << 20;
    unsigned hi12 = lo12 + (1u << 20);
    unsigned m = ws[CTRL_OFF + 6];

    __shared__ unsigned sh[64];
    __shared__ float buf[LBUF];
    __shared__ unsigned lcnt, gbase;
    if (threadIdx.x < 64) sh[threadIdx.x] = 0;
    if (threadIdx.x == 0) lcnt = 0;
    __syncthreads();

    float* cand = (float*)(ws + CAND_OFF);
    unsigned* cnt = ws + CTRL_OFF + 3;

    long long n4 = n >> 2;
    long long tid = (long long)blockIdx.x * 256 + threadIdx.x;
    long long stride = (long long)gridDim.x * 256;
    const uint4* o4 = (const uint4*)ob;

    for (long long i = tid; i < n4; i += stride) {
        uint4 u4 = o4[i];
        unsigned us[4] = {u4.x, u4.y, u4.z, u4.w};
#pragma unroll
        for (int c = 0; c < 4; ++c) {
            unsigned u = us[c];
            // knowns have sign bit set -> u >= 2^31 > hi12 -> excluded
            if (u != 0u && u >= lo12 && u < hi12) {
                float x = lg[i * 4 + c];
                unsigned rB = u;
                unsigned d = u & 16383u;
                if (d < m || d >= 16384u - m)
                    rB = exact_bits(x);           // edge: resolve exactly
                atomicAdd(&sh[(rB >> 14) & 63u], 1u);
                unsigned li = atomicAdd(&lcnt, 1u);   // LDS atomic
                if (li < LBUF) buf[li] = x;
            }
        }
    }
    if (tid == 0) {  // scalar tail (empty for n % 4 == 0): direct append
        for (long long i = (n4 << 2); i < n; ++i) {
            unsigned u = ob[i];
            if (u != 0u && u >= lo12 && u < hi12) {
                float x = lg[i];
                unsigned rB = u;
                unsigned d = u & 16383u;
                if (d < m || d >= 16384u - m) rB = exact_bits(x);
                atomicAdd(&sh[(rB >> 14) & 63u], 1u);
                unsigned idx = atomicAdd(cnt, 1u);
                if (idx < CAND_CAP) cand[idx] = x;
            }
        }
    }
    __syncthreads();
    if (threadIdx.x < 64 && sh[threadIdx.x])
        atomicAdd(&ws[H64_OFF + threadIdx.x], sh[threadIdx.x]);
    // flush candidate buffer: one reservation per block
    if (threadIdx.x == 0) {
        // on LDS overflow, poison the count so kC takes the rescan fallback
        unsigned add = (lcnt > LBUF) ? (CAND_CAP + 1u) : lcnt;
        gbase = atomicAdd(cnt, add);
    }
    __syncthreads();
    unsigned c2 = lcnt < LBUF ? lcnt : LBUF;
    for (unsigned j = threadIdx.x; j < c2; j += 256) {
        unsigned gi = gbase + j;
        if (gi < CAND_CAP) cand[gi] = buf[j];
    }
}

// --- k4: select 2^14-wide window ------------------------------------------
__global__ void k4_sel64(unsigned* __restrict__ ws) {
    unsigned* ctrl = ws + CTRL_OFF;
    if (ctrl[0] == 0xFFFFFFFFu) return;
    if (threadIdx.x == 0) {
        long long kprime = (long long)ctrl[1];
        long long cum = 0;
        int s = 0;
        long long kpp = 1;
        for (int j = 63; j >= 0; --j) {
            unsigned v = ws[H64_OFF + j];
            if (cum + (long long)v >= kprime) {
                s = j;
                kpp = kprime - cum;
                break;
            }
            cum += v;
        }
        ctrl[4] = (ctrl[0] << 20) + ((unsigned)s << 14);
        ctrl[5] = (unsigned)kpp;
    }
}

// --- kC: exact histogram over the selected window (candidate-list scan) ---
__global__ __launch_bounds__(256) void kC_histwin(
    const float* __restrict__ lg, const unsigned* __restrict__ ob,
    unsigned* __restrict__ ws, long long n) {
    unsigned wlo = ws[CTRL_OFF + 4];
    if (wlo == 0xFFFFFFFFu) return;
    unsigned whi = wlo + 16384u;
    unsigned m = ws[CTRL_OFF + 6];
    unsigned b12 = ws[CTRL_OFF + 0];
    unsigned lo12 = b12 << 20;
    unsigned hi12 = lo12 + (1u << 20);
    unsigned glo = (wlo - lo12 > m) ? wlo - m : lo12;
    unsigned ghi = (hi12 - whi > m) ? whi + m : hi12;
    unsigned count = ws[CTRL_OFF + 3];

    long long tid = (long long)blockIdx.x * 256 + threadIdx.x;
    long long stride = (long long)gridDim.x * 256;

    if (count <= CAND_CAP) {
        const float* cand = (const float*)(ws + CAND_OFF);
        for (long long i = tid; i < (long long)count; i += stride) {
            float x = cand[i];
            float spd;
            unsigned u = refine_A(x, &spd);   // bit-identical to stored bits
            if (u >= glo && u < ghi) {
                unsigned eb = exact_bits(x);
                unsigned rB = u;
                unsigned d = u & 16383u;
                if (d < m || d >= 16384u - m) rB = eb;
                if (rB >= wlo && rB < whi) {
                    unsigned off = eb - wlo;
                    if (off < 16384u) atomicAdd(&ws[HC_OFF + off], 1u);
                }
            }
        }
    } else {
        // overflow fallback: rescan full out array (never expected)
        long long n4 = n >> 2;
        const uint4* o4 = (const uint4*)ob;
        for (long long i = tid; i < n4; i += stride) {
            uint4 u4 = o4[i];
            unsigned us[4] = {u4.x, u4.y, u4.z, u4.w};
#pragma unroll
            for (int c = 0; c < 4; ++c) {
                unsigned u = us[c];
                if (u != 0u && u >= glo && u < ghi) {
                    float x = lg[i * 4 + c];
                    unsigned eb = exact_bits(x);
                    unsigned rB = u;
                    unsigned d = u & 16383u;
                    if (d < m || d >= 16384u - m) rB = eb;
                    if (rB >= wlo && rB < whi) {
                        unsigned off = eb - wlo;
                        if (off < 16384u) atomicAdd(&ws[HC_OFF + off], 1u);
                    }
                }
            }
        }
        if (tid == 0) {
            for (long long i = (n4 << 2); i < n; ++i) {
                unsigned u = ob[i];
                if (u != 0u && u >= glo && u < ghi) {
                    unsigned eb = exact_bits(lg[i]);
                    unsigned rB = u;
                    unsigned d = u & 16383u;
                    if (d < m || d >= 16384u - m) rB = eb;
                    if (rB >= wlo && rB < whi) {
                        unsigned off = eb - wlo;
                        if (off < 16384u) atomicAdd(&ws[HC_OFF + off], 1u);
                    }
                }
            }
        }
    }
}

// --- k6: exact threshold bits from histC ----------------------------------
__global__ __launch_bounds__(1024) void k6_selwin(unsigned* __restrict__ ws) {
    unsigned* ctrl = ws + CTRL_OFF;
    if (ctrl[4] == 0xFFFFFFFFu) return;
    __shared__ unsigned long long csum[1024];
    int t = threadIdx.x;
    unsigned long long s = 0;
    for (int j = 0; j < 16; ++j) s += ws[HC_OFF + t * 16 + j];
    csum[t] = s;
    __syncthreads();
    if (t == 0) {
        long long kpp = (long long)ctrl[5];
        long long cum = 0;
        int sel = 0;
        long long rem = kpp;
        for (int c = 1023; c >= 0; --c) {
            if (cum + (long long)csum[c] >= kpp) {
                sel = c;
                rem = kpp - cum;
                break;
            }
            cum += csum[c];
        }
        long long cc = 0;
        int bsel = 0;
        for (int j = 15; j >= 0; --j) {
            unsigned v = ws[HC_OFF + sel * 16 + j];
            if (cc + (long long)v >= rem) {
                bsel = j;
                break;
            }
            cc += v;
        }
        ctrl[2] = ctrl[4] + (unsigned)(sel * 16 + bsel);
    }
}

// --- kD: final in-place rewrite of out (2x-unrolled stream) ----------------
__device__ __forceinline__ unsigned kD_elem(unsigned u, unsigned thr,
                                            unsigned m,
                                            const float* __restrict__ lg,
                                            long long idx) {
    if (u & 0x80000000u) return u ^ 0x80000000u;    // known: restore loss
    unsigned udiff = (u > thr) ? u - thr : thr - u;
    if (udiff <= m) {                               // banded: exact decision
        unsigned eb = exact_bits(lg[idx]);
        return (eb > thr) ? 0u : eb;
    }
    return (u > thr) ? 0u : u;
}

__global__ __launch_bounds__(256) void kD_final(
    const float* __restrict__ lg, unsigned* __restrict__ ob,
    const unsigned* __restrict__ ws, long long n) {
    unsigned thr = ws[CTRL_OFF + 2];
    unsigned m = ws[CTRL_OFF + 6];

    long long n8 = n >> 3;
    long long tid = (long long)blockIdx.x * 256 + threadIdx.x;
    long long stride = (long long)gridDim.x * 256;
    uint4* o4 = (uint4*)ob;

    for (long long i = tid; i < n8; i += stride) {
        uint4 ua = o4[2 * i];
        uint4 ub = o4[2 * i + 1];
        uint4 va, vb;
        long long base = i * 8;
        va.x = kD_elem(ua.x, thr, m, lg, base + 0);
        va.y = kD_elem(ua.y, thr, m, lg, base + 1);
        va.z = kD_elem(ua.z, thr, m, lg, base + 2);
        va.w = kD_elem(ua.w, thr, m, lg, base + 3);
        vb.x = kD_elem(ub.x, thr, m, lg, base + 4);
        vb.y = kD_elem(ub.y, thr, m, lg, base + 5);
        vb.z = kD_elem(ub.z, thr, m, lg, base + 6);
        vb.w = kD_elem(ub.w, thr, m, lg, base + 7);
        o4[2 * i] = va;
        o4[2 * i + 1] = vb;
    }
    if (tid == 0) {
        for (long long i = (n8 << 3); i < n; ++i)
            ob[i] = kD_elem(ob[i], thr, m, lg, i);
    }
}

extern "C" void kernel_launch(void* const* d_in, const int* in_sizes, int n_in,
                              void* d_out, int out_size, void* d_ws, size_t ws_size,
                              hipStream_t stream) {
    const float* lg = (const float*)d_in[0];
    const float* tg = (const float*)d_in[1];
    const int* epoch = (const int*)d_in[2];
    float* out = (float*)d_out;
    unsigned* ob = (unsigned*)d_out;
    unsigned* ws = (unsigned*)d_ws;
    long long n = (long long)in_sizes[0];

    hipMemsetAsync(d_ws, 0, (size_t)ZERO_WORDS * 4, stream);

    const int blocks = 2048, threads = 256;
    kA_store_hist<<<blocks, threads, 0, stream>>>(lg, tg, out, ws, n);
    k2_sel12<<<1, 256, 0, stream>>>(ws, epoch);
    kB_hist64<<<blocks, threads, 0, stream>>>(lg, ob, ws, n);
    k4_sel64<<<1, 64, 0, stream>>>(ws);
    kC_histwin<<<1024, threads, 0, stream>>>(lg, ob, ws, n);
    k6_selwin<<<1, 1024, 0, stream>>>(ws);
    kD_final<<<blocks, threads, 0, stream>>>(lg, ob, ws, n);
}

// Round 8
// 242.026 us; speedup vs baseline: 1.0970x; 1.0638x over previous
//
#include <hip/hip_runtime.h>
#include <math.h>

// native clang vector types (required by __builtin_nontemporal_*)
typedef float    f32x4 __attribute__((ext_vector_type(4)));
typedef unsigned u32x4 __attribute__((ext_vector_type(4)));

// ws layout (uint32 words):
//   [0     .. 16384)  histC  (exact low-bits hist over selected 2^14 window)
//   [16384 .. 20480)  hist12 (top-12-bit histogram)
//   [20480 .. 20544)  hist64 (64 sub-bins of width 2^14 within selected b12)
//   [20544 .. 20560)  ctrl: [0]=b12 (0xFFFFFFFF=none) [1]=kprime [2]=thr_bits
//                           [3]=cand_count [4]=win_lo_bits (0xFFFFFFFF=none)
//                           [5]=kpp [6]=m_bin
//   [20560 .. +CAP)   candidate x values (float) of selected b12
#define HC_OFF     0u
#define H12_OFF    16384u
#define H64_OFF    20480u
#define CTRL_OFF   20544u
#define ZERO_WORDS 20560u
#define CAND_OFF   20560u
#define CAND_CAP   900000u     // 3.6 MB total ws use (proven available in r3)
#define LBUF       2048u       // per-block LDS candidate buffer

#define FLOOR_BITS 0x36000000u // bits(2^-19): below this, cheap is unreliable

// --- exact softplus (UNCHANGED from passing rounds 1-6) ------------------
__device__ __forceinline__ float softplus_exact(float x) {
    float ax = fabsf(x);
    float e = (float)exp(-(double)ax);
    float l = (float)log1p((double)e);
    return fmaxf(x, 0.0f) + l;
}
__device__ __forceinline__ unsigned exact_bits(float x) {
    return __float_as_uint(softplus_exact(x));
}

// --- refinement core: margin-gated exact, given precomputed ax/e/sp ------
// DETERMINISTIC function of x: recomputing reproduces stored bits exactly.
__device__ __forceinline__ unsigned refine_core(float x, float ax, float e,
                                                float sp) {
    unsigned cb = __float_as_uint(sp);
    float mf = 64.0f + 8.0f * ax;
    if (x < 0.0f) mf += __builtin_amdgcn_rcpf(e);   // e^{ax} term
    bool need = (cb < FLOOR_BITS) || (mf >= 524288.0f);
    if (!need) {
        unsigned m = (unsigned)mf;
        unsigned low = cb & 0xFFFFFu;
        need = (low < m) || (low >= 0x100000u - m);
    }
    if (need) cb = exact_bits(x);
    return cb;
}
__device__ __forceinline__ unsigned refine_A(float x, float* spo) {
    float ax = fabsf(x);
    float e = __expf(-ax);
    float sp = fmaxf(x, 0.0f) + __logf(1.0f + e);
    *spo = sp;
    return refine_core(x, ax, e, sp);
}

// --- kA per-element: branchless shared exp/log core ----------------------
__device__ __forceinline__ unsigned kA_elem(float x, float t,
                                            unsigned* __restrict__ sh) {
    float ax = fabsf(x);
    float e = __expf(-ax);
    float sp = fmaxf(x, 0.0f) + __logf(1.0f + e);   // shared by both paths
    unsigned outb;
    if (isnan(t)) {
        unsigned cb = refine_core(x, ax, e, sp);    // bit == refine_A(x)
        if (cb != 0u) atomicAdd(&sh[cb >> 20], 1u);
        outb = cb;
    } else {
        float loss = sp - x * t;                    // >= 0 always
        outb = __float_as_uint(loss) ^ 0x80000000u; // sign tag: known
    }
    return outb;
}

// --- kA: stream logits+targets; store refined bits to out; hist12 --------
// unknown: out = +loss (refined bits). known: out = -(loss) (sign tag).
// Software-pipelined: next iteration's 64 B/lane prefetched before compute.
__global__ __launch_bounds__(256) void kA_store_hist(
    const float* __restrict__ lg, const float* __restrict__ tg,
    float* __restrict__ out, unsigned* __restrict__ ws, long long n) {
    __shared__ unsigned sh[4096];
    for (int i = threadIdx.x; i < 4096; i += 256) sh[i] = 0;
    __syncthreads();

    long long n8 = n >> 3;
    long long tid = (long long)blockIdx.x * 256 + threadIdx.x;
    long long stride = (long long)gridDim.x * 256;
    const f32x4* lg4 = (const f32x4*)lg;
    const f32x4* tg4 = (const f32x4*)tg;
    f32x4* out4 = (f32x4*)out;

    long long i = tid;
    f32x4 xa, xb, ta, tb;
    if (i < n8) {
        xa = lg4[2 * i];
        xb = lg4[2 * i + 1];
        ta = __builtin_nontemporal_load(&tg4[2 * i]);
        tb = __builtin_nontemporal_load(&tg4[2 * i + 1]);
    }
    while (i < n8) {
        long long j = i + stride;
        f32x4 nxa, nxb, nta, ntb;
        if (j < n8) {                       // prefetch next tile
            nxa = lg4[2 * j];
            nxb = lg4[2 * j + 1];
            nta = __builtin_nontemporal_load(&tg4[2 * j]);
            ntb = __builtin_nontemporal_load(&tg4[2 * j + 1]);
        }
        f32x4 oa, ob_;
        oa.x = __uint_as_float(kA_elem(xa.x, ta.x, sh));
        oa.y = __uint_as_float(kA_elem(xa.y, ta.y, sh));
        oa.z = __uint_as_float(kA_elem(xa.z, ta.z, sh));
        oa.w = __uint_as_float(kA_elem(xa.w, ta.w, sh));
        ob_.x = __uint_as_float(kA_elem(xb.x, tb.x, sh));
        ob_.y = __uint_as_float(kA_elem(xb.y, tb.y, sh));
        ob_.z = __uint_as_float(kA_elem(xb.z, tb.z, sh));
        ob_.w = __uint_as_float(kA_elem(xb.w, tb.w, sh));
        out4[2 * i] = oa;
        out4[2 * i + 1] = ob_;
        xa = nxa; xb = nxb; ta = nta; tb = ntb;
        i = j;
    }
    if (tid == 0) {   // scalar tail (n % 8 == 0 here; kept for generality)
        for (long long q = (n8 << 3); q < n; ++q)
            out[q] = __uint_as_float(kA_elem(lg[q], tg[q], sh));
    }
    __syncthreads();
    unsigned* hist12 = ws + H12_OFF;
    for (int q = threadIdx.x; q < 4096; q += 256)
        if (sh[q]) atomicAdd(&hist12[q], sh[q]);
}

// --- k2: select 12-bit bin; compute k, kprime, and bin-wide margin -------
__global__ __launch_bounds__(256) void k2_sel12(
    unsigned* __restrict__ ws, const int* __restrict__ epoch_ptr) {
    const unsigned* hist12 = ws + H12_OFF;
    unsigned* ctrl = ws + CTRL_OFF;
    __shared__ unsigned long long chunk[256];
    int t = threadIdx.x;
    unsigned long long s = 0;
    for (int j = 0; j < 16; ++j) s += hist12[t * 16 + j];
    chunk[t] = s;
    __syncthreads();
    if (t == 0) {
        unsigned long long tot = 0;
        for (int c = 0; c < 256; ++c) tot += chunk[c];
        int epoch = epoch_ptr[0];
        float percent = fminf((float)epoch * 0.1f, 1.0f);
        float nf = (float)tot;              // astype(float32)
        float kr = rintf(nf * percent);     // jnp.round half-to-even
        long long k = (long long)kr;        // astype(int32)
        if (k < 1) k = 1;

        long long cum = 0;
        int b = -1;
        long long kprime = 0;
        for (int c = 255; c >= 0; --c) {
            if (cum + (long long)chunk[c] >= k) {
                long long cc = cum;
                for (int j = 15; j >= 0; --j) {
                    unsigned v = hist12[c * 16 + j];
                    if (cc + (long long)v >= k) {
                        b = c * 16 + j;
                        kprime = k - cc;
                        break;
                    }
                    cc += v;
                }
                break;
            }
            cum += chunk[c];
        }
        ctrl[0] = (unsigned)b;
        ctrl[1] = (unsigned)kprime;
        if (b < 0) {
            ctrl[2] = 0u;                   // threshold = 0.0f
            ctrl[4] = 0xFFFFFFFFu;          // no window
            ctrl[6] = 0u;
        } else {
            // bin-wide margin: worst per-element cheap-error over the bin's
            // x-range (unknown loss = softplus(x) is monotone in x).
            unsigned lo12 = (unsigned)b << 20;
            double vlo = (double)__uint_as_float(lo12);
            double vhi = (double)__uint_as_float(lo12 + 0xFFFFFu);
            double mb = 1e9;
            if (vlo > 1e-30) {
                double xlo = vlo + log1p(-exp(-vlo)) - 0.001;  // inv_softplus
                double xhi = vhi + log1p(-exp(-vhi)) + 0.001;
                double axmax = fmax(fabs(xlo), fabs(xhi));
                mb = 64.0 + 8.0 * ceil(axmax);
                if (xlo < 0.0) mb += exp(fmin(-xlo, 30.0));
                mb *= 2.0;                  // safety factor
            }
            ctrl[6] = (mb >= 8192.0) ? 8192u : (unsigned)mb;
        }
    }
}

// --- kB: 64-sub-bin histogram within selected bin + candidate compaction --
// Compaction per-block LDS-buffered; main stream software-pipelined.
__global__ __launch_bounds__(256) void kB_hist64(
    const float* __restrict__ lg, const unsigned* __restrict__ ob,
    unsigned* __restrict__ ws, long long n) {
    unsigned b12 = ws[CTRL_OFF + 0];
    if (b12 == 0xFFFFFFFFu) return;
    unsigned lo12 = b12 << 20;
    unsigned hi12 = lo12 + (1u << 20);
    unsigned m = ws[CTRL_OFF + 6];

    __shared__ unsigned sh[64];
    __shared__ float buf[LBUF];
    __shared__ unsigned lcnt, gbase;
    if (threadIdx.x < 64) sh[threadIdx.x] = 0;
    if (threadIdx.x == 0) lcnt = 0;
    __syncthreads();

    float* cand = (float*)(ws + CAND_OFF);
    unsigned* cnt = ws + CTRL_OFF + 3;

    long long n4 = n >> 2;
    long long tid = (long long)blockIdx.x * 256 + threadIdx.x;
    long long stride = (long long)gridDim.x * 256;
    const u32x4* o4 = (const u32x4*)ob;

    long long i = tid;
    u32x4 u4;
    if (i < n4) u4 = o4[i];
    while (i < n4) {
        long long j = i + stride;
        u32x4 nu4;
        if (j < n4) nu4 = o4[j];            // prefetch next tile
        unsigned us[4] = {u4.x, u4.y, u4.z, u4.w};
#pragma unroll
        for (int c = 0; c < 4; ++c) {
            unsigned u = us[c];
            // knowns have sign bit set -> u >= 2^31 > hi12 -> excluded
            if (u != 0u && u >= lo12 && u < hi12) {
                float x = lg[i * 4 + c];
                unsigned rB = u;
                unsigned d = u & 16383u;
                if (d < m || d >= 16384u - m)
                    rB = exact_bits(x);           // edge: resolve exactly
                atomicAdd(&sh[(rB >> 14) & 63u], 1u);
                unsigned li = atomicAdd(&lcnt, 1u);   // LDS atomic
                if (li < LBUF) buf[li] = x;
            }
        }
        u4 = nu4;
        i = j;
    }
    if (tid == 0) {  // scalar tail (empty for n % 4 == 0): direct append
        for (long long q = (n4 << 2); q < n; ++q) {
            unsigned u = ob[q];
            if (u != 0u && u >= lo12 && u < hi12) {
                float x = lg[q];
                unsigned rB = u;
                unsigned d = u & 16383u;
                if (d < m || d >= 16384u - m) rB = exact_bits(x);
                atomicAdd(&sh[(rB >> 14) & 63u], 1u);
                unsigned idx = atomicAdd(cnt, 1u);
                if (idx < CAND_CAP) cand[idx] = x;
            }
        }
    }
    __syncthreads();
    if (threadIdx.x < 64 && sh[threadIdx.x])
        atomicAdd(&ws[H64_OFF + threadIdx.x], sh[threadIdx.x]);
    // flush candidate buffer: one reservation per block
    if (threadIdx.x == 0) {
        // on LDS overflow, poison the count so kC takes the rescan fallback
        unsigned add = (lcnt > LBUF) ? (CAND_CAP + 1u) : lcnt;
        gbase = atomicAdd(cnt, add);
    }
    __syncthreads();
    unsigned c2 = lcnt < LBUF ? lcnt : LBUF;
    for (unsigned q = threadIdx.x; q < c2; q += 256) {
        unsigned gi = gbase + q;
        if (gi < CAND_CAP) cand[gi] = buf[q];
    }
}

// --- k4: select 2^14-wide window ------------------------------------------
__global__ void k4_sel64(unsigned* __restrict__ ws) {
    unsigned* ctrl = ws + CTRL_OFF;
    if (ctrl[0] == 0xFFFFFFFFu) return;
    if (threadIdx.x == 0) {
        long long kprime = (long long)ctrl[1];
        long long cum = 0;
        int s = 0;
        long long kpp = 1;
        for (int j = 63; j >= 0; --j) {
            unsigned v = ws[H64_OFF + j];
            if (cum + (long long)v >= kprime) {
                s = j;
                kpp = kprime - cum;
                break;
            }
            cum += v;
        }
        ctrl[4] = (ctrl[0] << 20) + ((unsigned)s << 14);
        ctrl[5] = (unsigned)kpp;
    }
}

// --- kC: exact histogram over the selected window (candidate-list scan) ---
__global__ __launch_bounds__(256) void kC_histwin(
    const float* __restrict__ lg, const unsigned* __restrict__ ob,
    unsigned* __restrict__ ws, long long n) {
    unsigned wlo = ws[CTRL_OFF + 4];
    if (wlo == 0xFFFFFFFFu) return;
    unsigned whi = wlo + 16384u;
    unsigned m = ws[CTRL_OFF + 6];
    unsigned b12 = ws[CTRL_OFF + 0];
    unsigned lo12 = b12 << 20;
    unsigned hi12 = lo12 + (1u << 20);
    unsigned glo = (wlo - lo12 > m) ? wlo - m : lo12;
    unsigned ghi = (hi12 - whi > m) ? whi + m : hi12;
    unsigned count = ws[CTRL_OFF + 3];

    long long tid = (long long)blockIdx.x * 256 + threadIdx.x;
    long long stride = (long long)gridDim.x * 256;

    if (count <= CAND_CAP) {
        const float* cand = (const float*)(ws + CAND_OFF);
        for (long long i = tid; i < (long long)count; i += stride) {
            float x = cand[i];
            float spd;
            unsigned u = refine_A(x, &spd);   // bit-identical to stored bits
            if (u >= glo && u < ghi) {
                unsigned eb = exact_bits(x);
                unsigned rB = u;
                unsigned d = u & 16383u;
                if (d < m || d >= 16384u - m) rB = eb;
                if (rB >= wlo && rB < whi) {
                    unsigned off = eb - wlo;
                    if (off < 16384u) atomicAdd(&ws[HC_OFF + off], 1u);
                }
            }
        }
    } else {
        // overflow fallback: rescan full out array (never expected)
        long long n4 = n >> 2;
        const u32x4* o4 = (const u32x4*)ob;
        for (long long i = tid; i < n4; i += stride) {
            u32x4 u4 = o4[i];
            unsigned us[4] = {u4.x, u4.y, u4.z, u4.w};
#pragma unroll
            for (int c = 0; c < 4; ++c) {
                unsigned u = us[c];
                if (u != 0u && u >= glo && u < ghi) {
                    float x = lg[i * 4 + c];
                    unsigned eb = exact_bits(x);
                    unsigned rB = u;
                    unsigned d = u & 16383u;
                    if (d < m || d >= 16384u - m) rB = eb;
                    if (rB >= wlo && rB < whi) {
                        unsigned off = eb - wlo;
                        if (off < 16384u) atomicAdd(&ws[HC_OFF + off], 1u);
                    }
                }
            }
        }
        if (tid == 0) {
            for (long long i = (n4 << 2); i < n; ++i) {
                unsigned u = ob[i];
                if (u != 0u && u >= glo && u < ghi) {
                    unsigned eb = exact_bits(lg[i]);
                    unsigned rB = u;
                    unsigned d = u & 16383u;
                    if (d < m || d >= 16384u - m) rB = eb;
                    if (rB >= wlo && rB < whi) {
                        unsigned off = eb - wlo;
                        if (off < 16384u) atomicAdd(&ws[HC_OFF + off], 1u);
                    }
                }
            }
        }
    }
}

// --- k6: exact threshold bits from histC ----------------------------------
__global__ __launch_bounds__(1024) void k6_selwin(unsigned* __restrict__ ws) {
    unsigned* ctrl = ws + CTRL_OFF;
    if (ctrl[4] == 0xFFFFFFFFu) return;
    __shared__ unsigned long long csum[1024];
    int t = threadIdx.x;
    unsigned long long s = 0;
    for (int j = 0; j < 16; ++j) s += ws[HC_OFF + t * 16 + j];
    csum[t] = s;
    __syncthreads();
    if (t == 0) {
        long long kpp = (long long)ctrl[5];
        long long cum = 0;
        int sel = 0;
        long long rem = kpp;
        for (int c = 1023; c >= 0; --c) {
            if (cum + (long long)csum[c] >= kpp) {
                sel = c;
                rem = kpp - cum;
                break;
            }
            cum += csum[c];
        }
        long long cc = 0;
        int bsel = 0;
        for (int j = 15; j >= 0; --j) {
            unsigned v = ws[HC_OFF + sel * 16 + j];
            if (cc + (long long)v >= rem) {
                bsel = j;
                break;
            }
            cc += v;
        }
        ctrl[2] = ctrl[4] + (unsigned)(sel * 16 + bsel);
    }
}

// --- kD: final in-place rewrite of out (software-pipelined stream) --------
__device__ __forceinline__ unsigned kD_elem(unsigned u, unsigned thr,
                                            unsigned m,
                                            const float* __restrict__ lg,
                                            long long idx) {
    if (u & 0x80000000u) return u ^ 0x80000000u;    // known: restore loss
    unsigned udiff = (u > thr) ? u - thr : thr - u;
    if (udiff <= m) {                               // banded: exact decision
        unsigned eb = exact_bits(lg[idx]);
        return (eb > thr) ? 0u : eb;
    }
    return (u > thr) ? 0u : u;
}

__global__ __launch_bounds__(256) void kD_final(
    const float* __restrict__ lg, unsigned* __restrict__ ob,
    const unsigned* __restrict__ ws, long long n) {
    unsigned thr = ws[CTRL_OFF + 2];
    unsigned m = ws[CTRL_OFF + 6];

    long long n8 = n >> 3;
    long long tid = (long long)blockIdx.x * 256 + threadIdx.x;
    long long stride = (long long)gridDim.x * 256;
    u32x4* o4 = (u32x4*)ob;

    long long i = tid;
    u32x4 ua, ub;
    if (i < n8) {
        ua = o4[2 * i];
        ub = o4[2 * i + 1];
    }
    while (i < n8) {
        long long j = i + stride;
        u32x4 nua, nub;
        if (j < n8) {                       // prefetch next tile
            nua = o4[2 * j];
            nub = o4[2 * j + 1];
        }
        u32x4 va, vb;
        long long base = i * 8;
        va.x = kD_elem(ua.x, thr, m, lg, base + 0);
        va.y = kD_elem(ua.y, thr, m, lg, base + 1);
        va.z = kD_elem(ua.z, thr, m, lg, base + 2);
        va.w = kD_elem(ua.w, thr, m, lg, base + 3);
        vb.x = kD_elem(ub.x, thr, m, lg, base + 4);
        vb.y = kD_elem(ub.y, thr, m, lg, base + 5);
        vb.z = kD_elem(ub.z, thr, m, lg, base + 6);
        vb.w = kD_elem(ub.w, thr, m, lg, base + 7);
        __builtin_nontemporal_store(va, &o4[2 * i]);
        __builtin_nontemporal_store(vb, &o4[2 * i + 1]);
        ua = nua; ub = nub;
        i = j;
    }
    if (tid == 0) {
        for (long long q = (n8 << 3); q < n; ++q)
            ob[q] = kD_elem(ob[q], thr, m, lg, q);
    }
}

extern "C" void kernel_launch(void* const* d_in, const int* in_sizes, int n_in,
                              void* d_out, int out_size, void* d_ws, size_t ws_size,
                              hipStream_t stream) {
    const float* lg = (const float*)d_in[0];
    const float* tg = (const float*)d_in[1];
    const int* epoch = (const int*)d_in[2];
    float* out = (float*)d_out;
    unsigned* ob = (unsigned*)d_out;
    unsigned* ws = (unsigned*)d_ws;
    long long n = (long long)in_sizes[0];

    (void)hipMemsetAsync(d_ws, 0, (size_t)ZERO_WORDS * 4, stream);

    const int blocks = 2048, threads = 256;
    kA_store_hist<<<blocks, threads, 0, stream>>>(lg, tg, out, ws, n);
    k2_sel12<<<1, 256, 0, stream>>>(ws, epoch);
    kB_hist64<<<blocks, threads, 0, stream>>>(lg, ob, ws, n);
    k4_sel64<<<1, 64, 0, stream>>>(ws);
    kC_histwin<<<1024, threads, 0, stream>>>(lg, ob, ws, n);
    k6_selwin<<<1, 1024, 0, stream>>>(ws);
    kD_final<<<blocks, threads, 0, stream>>>(lg, ob, ws, n);
}